// Round 8
// baseline (105.052 us; speedup 1.0000x reference)
//
#include <hip/hip_runtime.h>
#include <hip/hip_bf16.h>
#include <math.h>

// B=4, N=512, T=288, L=128
#define NN 512
#define NT 288

// ---------------------------------------------------------------------------
// Kernel T: weight transpose (runs once per call, ~0.4 MB, L2-resident after).
// Wt[288][256]:  Wt[k][col]  = col<128 ? W1[col][k] : W2[col-128][k]
// Wpt[128][256]: Wpt[k][col] = col<128 ? Wp[col][k] : Wp[col-128][128+k]
// Writes coalesced; scattered reads are a one-time ~0.4 µs cost.
// ---------------------------------------------------------------------------
__global__ __launch_bounds__(256) void kT(
    const float* __restrict__ W1, const float* __restrict__ W2,
    const float* __restrict__ Wp,
    float* __restrict__ Wt, float* __restrict__ Wpt)
{
    int g = blockIdx.x * 256 + threadIdx.x;
    if (g < 288 * 256) {
        int k = g >> 8, col = g & 255;
        Wt[g] = (col < 128) ? W1[col * 288 + k] : W2[(col - 128) * 288 + k];
    } else {
        int h = g - 288 * 256;          // 0 .. 32767
        int k = h >> 8, col = h & 255;
        Wpt[h] = (col < 128) ? Wp[col * 256 + k]
                             : Wp[(col - 128) * 256 + 128 + k];
    }
}

// ---------------------------------------------------------------------------
// Kernel P: x -> x1,x2 (leaky) -> S12=[S1|S2] + row dots A,C.
// 256 blocks x 512 threads = (col 0..255, kh 0..1), 8 bn-rows per block.
// W via TRANSPOSED Wt/Wpt: lane col reads Wt[k][col] -> 64x4B = 4 cache
// lines per instr (was 64). x read with wave-uniform (scalarizable) global
// loads, L1-resident. No LDS staging in the GEMM loops, no mid-loop barriers.
// ---------------------------------------------------------------------------
__global__ __launch_bounds__(512) void kP(
    const float* __restrict__ x,    // [2048][288]
    const float* __restrict__ Wt,   // [288][256]
    const float* __restrict__ b1,   // [128]
    const float* __restrict__ b2,   // [128]
    const float* __restrict__ Wpt,  // [128][256]
    const float* __restrict__ bp,   // [128]
    const float* __restrict__ Wb,   // [128]
    const float* __restrict__ bb,   // [1]
    float* __restrict__ S12,        // ws [2048][256]
    float* __restrict__ Aarr,       // ws [2048]
    float* __restrict__ Carr)       // ws [2048]
{
    __shared__ __align__(16) float x12s[8 * 256];  // 8 KB
    __shared__ __align__(16) float ph[8 * 256];    // 8 KB
    __shared__ __align__(16) float s12s[8 * 257];  // 8.2 KB

    const int t   = threadIdx.x;
    const int bn0 = blockIdx.x * 8;
    const int col = t & 255;
    const int kh  = t >> 8;       // K-half

    // ---- G1: col of [x1|x2] for 8 rows; K=288 split 144/144 over kh ----
    const float* xb  = x + (size_t)bn0 * NT + kh * 144;   // wave-uniform
    const float* wtb = Wt + kh * 144 * 256 + col;         // coalesced over col

    float acc[8];
#pragma unroll
    for (int n = 0; n < 8; ++n) acc[n] = 0.0f;

    for (int k4 = 0; k4 < 36; ++k4) {
        float w0 = wtb[(k4 * 4 + 0) * 256];
        float w1 = wtb[(k4 * 4 + 1) * 256];
        float w2 = wtb[(k4 * 4 + 2) * 256];
        float w3 = wtb[(k4 * 4 + 3) * 256];
#pragma unroll
        for (int n = 0; n < 8; ++n) {
            float4 xv = *(const float4*)&xb[n * NT + k4 * 4];
            acc[n] = fmaf(w0, xv.x, acc[n]);
            acc[n] = fmaf(w1, xv.y, acc[n]);
            acc[n] = fmaf(w2, xv.z, acc[n]);
            acc[n] = fmaf(w3, xv.w, acc[n]);
        }
    }

    const float bias1 = (col < 128) ? b1[col] : b2[col - 128];
    if (kh) {
#pragma unroll
        for (int n = 0; n < 8; ++n) ph[n * 256 + col] = acc[n];
    }
    __syncthreads();
    if (!kh) {
#pragma unroll
        for (int n = 0; n < 8; ++n) {
            float v = acc[n] + ph[n * 256 + col] + bias1;
            x12s[n * 256 + col] = fmaxf(v, 0.2f * v);   // leaky
        }
    }
    __syncthreads();

    // ---- G2: col of [S1|S2] for 8 rows; K=128 split 64/64 over kh ----
    const int koff = (col < 128) ? 0 : 128;   // wave-uniform (64-lane quadrants)
    const float* wptb = Wpt + kh * 64 * 256 + col;
    const int kb2 = koff + kh * 64;

    float acc2[8];
#pragma unroll
    for (int n = 0; n < 8; ++n) acc2[n] = 0.0f;

    for (int k4 = 0; k4 < 16; ++k4) {
        float w0 = wptb[(k4 * 4 + 0) * 256];
        float w1 = wptb[(k4 * 4 + 1) * 256];
        float w2 = wptb[(k4 * 4 + 2) * 256];
        float w3 = wptb[(k4 * 4 + 3) * 256];
#pragma unroll
        for (int n = 0; n < 8; ++n) {
            float4 xv = *(const float4*)&x12s[n * 256 + kb2 + k4 * 4];
            acc2[n] = fmaf(w0, xv.x, acc2[n]);
            acc2[n] = fmaf(w1, xv.y, acc2[n]);
            acc2[n] = fmaf(w2, xv.z, acc2[n]);
            acc2[n] = fmaf(w3, xv.w, acc2[n]);
        }
    }

    const float bias2 = (col < 128) ? bp[col] : 0.0f;
    if (kh) {
#pragma unroll
        for (int n = 0; n < 8; ++n) ph[n * 256 + col] = acc2[n];
    }
    __syncthreads();
    if (!kh) {
#pragma unroll
        for (int n = 0; n < 8; ++n) {
            float sv = acc2[n] + ph[n * 256 + col] + bias2;
            S12[(size_t)(bn0 + n) * 256 + col] = sv;
            s12s[n * 257 + col] = sv;
        }
    }
    __syncthreads();

    // ---- per-row dots with Wb: 16 dots x 32 lanes ----
    {
        int lane32 = t & 31;
        int n = (t >> 5) & 7;
        int isC = t >> 8;
        int base = isC ? 128 : 0;
        float sum = 0.0f;
#pragma unroll
        for (int s = 0; s < 4; ++s) {
            int j = lane32 + s * 32;
            sum = fmaf(s12s[n * 257 + base + j], Wb[j], sum);
        }
#pragma unroll
        for (int m = 16; m >= 1; m >>= 1)
            sum += __shfl_xor(sum, m, 32);
        if (lane32 == 0) {
            if (isC) Carr[bn0 + n] = 0.6f * sum;
            else     Aarr[bn0 + n] = 0.6f * sum + bb[0];
        }
    }
}

// ---------------------------------------------------------------------------
// Kernel Q: fully-fused pairwise + mean-over-b + phase F (unchanged from R7).
// grid (16,16) = 32x32 output tile per block; ALL 4 b-slices in one block.
// ---------------------------------------------------------------------------
__global__ __launch_bounds__(512) void kQ(
    const float* __restrict__ S12,   // [2048][256]
    const float* __restrict__ Aarr,  // [2048]
    const float* __restrict__ Carr,  // [2048]
    const float* __restrict__ Wb,    // [128]
    const float* __restrict__ noise, // [512][512]
    float* __restrict__ out)         // [512][512]
{
    __shared__ __align__(16) float smem[32768];   // 128 KB
    float* S1t = smem;             // [4][128][32]
    float* S2t = smem + 16384;     // [4][128][32]

    const int t = threadIdx.x;
    const int bx = blockIdx.x, by = blockIdx.y;

    // ---- stage all 4 bz tiles: 8192 float4 tasks, 16 per thread ----
#pragma unroll
    for (int q = 0; q < 16; ++q) {
        int task = q * 512 + t;
        int isS2 = task >> 12;
        int r    = task & 4095;
        int bz   = r >> 10;
        int row  = (r >> 5) & 31;
        int c4   = r & 31;
        size_t src = (size_t)(bz * NN + (isS2 ? by : bx) * 32 + row) * 256
                     + (isS2 ? 128 : 0) + c4 * 4;
        float4 v = *(const float4*)&S12[src];
        float* dst = (isS2 ? S2t : S1t) + bz * 4096;
        int rw = row ^ ((c4 & 7) << 2);          // sw = ((l>>2)&7)<<2, l = 4c4+d
        dst[(c4 * 4 + 0) * 32 + rw] = v.x;
        dst[(c4 * 4 + 1) * 32 + rw] = v.y;
        dst[(c4 * 4 + 2) * 32 + rw] = v.z;
        dst[(c4 * 4 + 3) * 32 + rw] = v.w;
    }
    __syncthreads();

    const int lh = t >> 8;           // l-half
    const int bz = (t >> 6) & 3;     // b-slice (wave-uniform)
    const int s  = t & 63;
    const int i0 = (s >> 3) << 2, j0 = (s & 7) << 2;

    const float* S1b = S1t + bz * 4096 + lh * 64 * 32;
    const float* S2b = S2t + bz * 4096 + lh * 64 * 32;
    const float* wbp = Wb + lh * 64;

    float accv[16];
#pragma unroll
    for (int k = 0; k < 16; ++k) accv[k] = 0.0f;

    for (int l4 = 0; l4 < 16; ++l4) {
        const int sw = (l4 & 7) << 2;
        const int lrow = l4 * 4 * 32;
        float4 wv = *(const float4*)&wbp[l4 * 4];   // wave-uniform broadcast
        const float wl[4] = {wv.x, wv.y, wv.z, wv.w};
#pragma unroll
        for (int d = 0; d < 4; ++d) {
            float4 a = *(const float4*)&S1b[lrow + d * 32 + (i0 ^ sw)];
            float4 b = *(const float4*)&S2b[lrow + d * 32 + (j0 ^ sw)];
            float w = wl[d];
            float ai[4] = {a.x, a.y, a.z, a.w};
            float bj[4] = {b.x, b.y, b.z, b.w};
#pragma unroll
            for (int ii = 0; ii < 4; ++ii)
#pragma unroll
                for (int jj = 0; jj < 4; ++jj) {
                    float tv = ai[ii] + bj[jj];
                    accv[ii * 4 + jj] = fmaf(fabsf(tv), w, accv[ii * 4 + jj]);
                }
        }
    }

    // ---- reduce l-halves through LDS (alias dead S1t) ----
    float* red = smem;                    // 4096 floats
    const int tid2 = t & 255;             // (bz, s)
    __syncthreads();
    if (lh) {
#pragma unroll
        for (int q = 0; q < 4; ++q) {
            float4 v = {accv[4 * q], accv[4 * q + 1], accv[4 * q + 2], accv[4 * q + 3]};
            *(float4*)&red[q * 1024 + tid2 * 4] = v;
        }
    }
    __syncthreads();

    float sig[16];
    if (!lh) {
#pragma unroll
        for (int q = 0; q < 4; ++q) {
            float4 v = *(const float4*)&red[q * 1024 + tid2 * 4];
            accv[4 * q]     += v.x;
            accv[4 * q + 1] += v.y;
            accv[4 * q + 2] += v.z;
            accv[4 * q + 3] += v.w;
        }
        float Av[4], Cv[4];
#pragma unroll
        for (int ii = 0; ii < 4; ++ii) Av[ii] = Aarr[bz * NN + bx * 32 + i0 + ii];
#pragma unroll
        for (int jj = 0; jj < 4; ++jj) Cv[jj] = Carr[bz * NN + by * 32 + j0 + jj];
#pragma unroll
        for (int ii = 0; ii < 4; ++ii)
#pragma unroll
            for (int jj = 0; jj < 4; ++jj) {
                float lg = Av[ii] + Cv[jj] + 0.4f * accv[ii * 4 + jj];
                sig[ii * 4 + jj] = 1.0f / (1.0f + expf(-lg));
            }
        // ---- bz-reduce staging: bz>=1 write sigmoids ----
        float* redB = smem + 4096;        // 3072 floats
        if (bz) {
#pragma unroll
            for (int q = 0; q < 4; ++q) {
                float4 v = {sig[4 * q], sig[4 * q + 1], sig[4 * q + 2], sig[4 * q + 3]};
                *(float4*)&redB[(bz - 1) * 1024 + q * 256 + s * 4] = v;
            }
        }
    }
    __syncthreads();

    // ---- bz=0 threads sum 4 slices, publish p[16] ----
    float* redB = smem + 4096;
    float* redP = smem + 7168;            // 1024 floats
    if (t < 64) {                          // lh=0, bz=0, s=t
#pragma unroll
        for (int bzz = 0; bzz < 3; ++bzz)
#pragma unroll
            for (int q = 0; q < 4; ++q) {
                float4 v = *(const float4*)&redB[bzz * 1024 + q * 256 + t * 4];
                sig[4 * q]     += v.x;
                sig[4 * q + 1] += v.y;
                sig[4 * q + 2] += v.z;
                sig[4 * q + 3] += v.w;
            }
#pragma unroll
        for (int q = 0; q < 4; ++q) {
            float4 v = {sig[4 * q], sig[4 * q + 1], sig[4 * q + 2], sig[4 * q + 3]};
            *(float4*)&redP[t * 16 + q * 4] = v;
        }
    }
    __syncthreads();

    // ---- phase F: 256 threads, 4 outputs each ----
    if (t < 256) {
        int i   = t >> 3;                 // 0..31
        int j0f = (t & 7) * 4;            // 0..28
        int sP  = (t >> 5) * 8 + (t & 7);
        int k0  = ((t >> 3) & 3) * 4;
        float4 pv4 = *(const float4*)&redP[sP * 16 + k0];
        float pv[4] = {pv4.x, pv4.y, pv4.z, pv4.w};

        int gi = bx * 32 + i;
        size_t base = (size_t)gi * NN + by * 32 + j0f;
        float4 nz = *(const float4*)&noise[base];
        float nv[4] = {nz.x, nz.y, nz.z, nz.w};

        float4 o;
        float* op = (float*)&o;
#pragma unroll
        for (int c = 0; c < 4; ++c) {
            float p = 0.25f * pv[c];
            int gj = by * 32 + j0f + c;
            if (gj == gi) p = 0.0f;
            float lp = logf(p + 1e-10f) - log1pf(-p + 1e-10f);
            lp = fminf(fmaxf(lp, -10.0f), 10.0f);
            float lgs = logf(nv[c]) - log1pf(-nv[c]);
            op[c] = 1.0f / (1.0f + expf(-(lp + lgs) * 5.0f));
        }
        *(float4*)&out[base] = o;
    }
}

// ---------------------------------------------------------------------------
extern "C" void kernel_launch(void* const* d_in, const int* in_sizes, int n_in,
                              void* d_out, int out_size, void* d_ws, size_t ws_size,
                              hipStream_t stream) {
    const float* x     = (const float*)d_in[0];
    const float* W1    = (const float*)d_in[1];
    const float* b1    = (const float*)d_in[2];
    const float* W2    = (const float*)d_in[3];
    const float* b2    = (const float*)d_in[4];
    const float* Wp    = (const float*)d_in[5];
    const float* bp    = (const float*)d_in[6];
    const float* Wb    = (const float*)d_in[7];
    const float* bb    = (const float*)d_in[8];
    const float* noise = (const float*)d_in[9];

    float* ws   = (float*)d_ws;
    float* S12  = ws;                   // 524288 floats
    float* Aarr = ws + 524288;          // 2048
    float* Carr = Aarr + 2048;          // 2048
    float* Wt   = Carr + 2048;          // 288*256 = 73728
    float* Wpt  = Wt + 73728;           // 128*256 = 32768

    kT<<<416, 256, 0, stream>>>(W1, W2, Wp, Wt, Wpt);
    kP<<<256, 512, 0, stream>>>(x, Wt, b1, b2, Wpt, bp, Wb, bb,
                                S12, Aarr, Carr);
    kQ<<<dim3(16, 16), 512, 0, stream>>>(S12, Aarr, Carr, Wb, noise,
                                         (float*)d_out);
}

// Round 9
// 45.425 us; speedup vs baseline: 2.3127x; 2.3127x over previous
//
#include <hip/hip_runtime.h>
#include <hip/hip_bf16.h>
#include <math.h>

// B=4, N=512, T=288, L=128
#define NN 512
#define NT 288

// ---------------------------------------------------------------------------
// Kernel T: weight transpose (once per call, ~0.4 MB, L2-resident after).
// Wt[288][256]:  Wt[k][col]  = col<128 ? W1[col][k] : W2[col-128][k]
// Wpt[128][256]: Wpt[k][col] = col<128 ? Wp[col][k] : Wp[col-128][128+k]
// ---------------------------------------------------------------------------
__global__ __launch_bounds__(256) void kT(
    const float* __restrict__ W1, const float* __restrict__ W2,
    const float* __restrict__ Wp,
    float* __restrict__ Wt, float* __restrict__ Wpt)
{
    int g = blockIdx.x * 256 + threadIdx.x;
    if (g < 288 * 256) {
        int k = g >> 8, col = g & 255;
        Wt[g] = (col < 128) ? W1[col * 288 + k] : W2[(col - 128) * 288 + k];
    } else {
        int h = g - 288 * 256;          // 0 .. 32767
        int k = h >> 8, col = h & 255;
        Wpt[h] = (col < 128) ? Wp[col * 256 + k]
                             : Wp[(col - 128) * 256 + 128 + k];
    }
}

// ---------------------------------------------------------------------------
// Kernel P: x -> x1,x2 (leaky) -> S12=[S1|S2] + row dots A,C.
// Structure identical to the proven R6 kernel (x staged in LDS, broadcast
// reads, K split over thread-halves). ONLY change: W read from transposed
// Wt/Wpt (coalesced: 4 cache lines/instr instead of 64).
// #pragma unroll 1 on the k4 loops prevents the R8 unroll->hoist->spill.
// ---------------------------------------------------------------------------
__global__ __launch_bounds__(512) void kP(
    const float* __restrict__ x,    // [2048][288]
    const float* __restrict__ Wt,   // [288][256]
    const float* __restrict__ b1,   // [128]
    const float* __restrict__ b2,   // [128]
    const float* __restrict__ Wpt,  // [128][256]
    const float* __restrict__ bp,   // [128]
    const float* __restrict__ Wb,   // [128]
    const float* __restrict__ bb,   // [1]
    float* __restrict__ S12,        // ws [2048][256]
    float* __restrict__ Aarr,       // ws [2048]
    float* __restrict__ Carr)       // ws [2048]
{
    __shared__ __align__(16) float xs[8 * NT];     // 9 KB; aliased s12s[8][257] later
    __shared__ __align__(16) float x12s[8 * 256];  // 8 KB
    __shared__ __align__(16) float ph[8 * 256];    // 8 KB

    const int t   = threadIdx.x;
    const int bn0 = blockIdx.x * 8;
    const int col = t & 255;
    const int kh  = t >> 8;       // K-half

    // stage 8 x-rows (576 float4)
    for (int q = 0; q < 2; ++q) {
        int idx = q * 512 + t;
        if (idx < 576) {
            int row = idx / 72, c4 = idx % 72;
            *(float4*)&xs[row * NT + c4 * 4] =
                *(const float4*)&x[(size_t)(bn0 + row) * NT + c4 * 4];
        }
    }
    __syncthreads();

    // ---- G1: col of [x1|x2] for 8 rows; K=288 split 144/144 over kh ----
    const float* wtb = Wt + kh * 144 * 256 + col;   // coalesced over col
    const int kb1 = kh * 144;
    const float bias1 = (col < 128) ? b1[col] : b2[col - 128];

    float acc[8];
#pragma unroll
    for (int n = 0; n < 8; ++n) acc[n] = 0.0f;

#pragma unroll 1
    for (int k4 = 0; k4 < 36; ++k4) {
        float w0 = wtb[(k4 * 4 + 0) * 256];
        float w1 = wtb[(k4 * 4 + 1) * 256];
        float w2 = wtb[(k4 * 4 + 2) * 256];
        float w3 = wtb[(k4 * 4 + 3) * 256];
#pragma unroll
        for (int n = 0; n < 8; ++n) {
            float4 xv = *(const float4*)&xs[n * NT + kb1 + k4 * 4];
            acc[n] = fmaf(w0, xv.x, acc[n]);
            acc[n] = fmaf(w1, xv.y, acc[n]);
            acc[n] = fmaf(w2, xv.z, acc[n]);
            acc[n] = fmaf(w3, xv.w, acc[n]);
        }
    }
    if (kh) {
#pragma unroll
        for (int n = 0; n < 8; ++n) ph[n * 256 + col] = acc[n];
    }
    __syncthreads();
    if (!kh) {
#pragma unroll
        for (int n = 0; n < 8; ++n) {
            float v = acc[n] + ph[n * 256 + col] + bias1;
            x12s[n * 256 + col] = fmaxf(v, 0.2f * v);   // leaky
        }
    }
    __syncthreads();

    // ---- G2: col of [S1|S2] for 8 rows; K=128 split 64/64 over kh ----
    const int koff = (col < 128) ? 0 : 128;   // wave-uniform (64-lane quadrants)
    const float* wptb = Wpt + kh * 64 * 256 + col;
    const float bias2 = (col < 128) ? bp[col] : 0.0f;
    const int kb2 = koff + kh * 64;

    float acc2[8];
#pragma unroll
    for (int n = 0; n < 8; ++n) acc2[n] = 0.0f;

#pragma unroll 1
    for (int k4 = 0; k4 < 16; ++k4) {
        float w0 = wptb[(k4 * 4 + 0) * 256];
        float w1 = wptb[(k4 * 4 + 1) * 256];
        float w2 = wptb[(k4 * 4 + 2) * 256];
        float w3 = wptb[(k4 * 4 + 3) * 256];
#pragma unroll
        for (int n = 0; n < 8; ++n) {
            float4 xv = *(const float4*)&x12s[n * 256 + kb2 + k4 * 4];
            acc2[n] = fmaf(w0, xv.x, acc2[n]);
            acc2[n] = fmaf(w1, xv.y, acc2[n]);
            acc2[n] = fmaf(w2, xv.z, acc2[n]);
            acc2[n] = fmaf(w3, xv.w, acc2[n]);
        }
    }
    if (kh) {
#pragma unroll
        for (int n = 0; n < 8; ++n) ph[n * 256 + col] = acc2[n];
    }
    __syncthreads();

    float* s12s = xs;   // alias: xs dead after G1
    if (!kh) {
#pragma unroll
        for (int n = 0; n < 8; ++n) {
            float sv = acc2[n] + ph[n * 256 + col] + bias2;
            S12[(size_t)(bn0 + n) * 256 + col] = sv;
            s12s[n * 257 + col] = sv;
        }
    }
    __syncthreads();

    // ---- per-row dots with Wb: 16 dots x 32 lanes ----
    {
        int lane32 = t & 31;
        int n = (t >> 5) & 7;
        int isC = t >> 8;
        int base = isC ? 128 : 0;
        float sum = 0.0f;
#pragma unroll
        for (int s = 0; s < 4; ++s) {
            int j = lane32 + s * 32;
            sum = fmaf(s12s[n * 257 + base + j], Wb[j], sum);
        }
#pragma unroll
        for (int m = 16; m >= 1; m >>= 1)
            sum += __shfl_xor(sum, m, 32);
        if (lane32 == 0) {
            if (isC) Carr[bn0 + n] = 0.6f * sum;
            else     Aarr[bn0 + n] = 0.6f * sum + bb[0];
        }
    }
}

// ---------------------------------------------------------------------------
// Kernel Q: fully-fused pairwise + mean-over-b + phase F (unchanged, R7-verified).
// grid (16,16) = 32x32 output tile per block; ALL 4 b-slices in one block.
// ---------------------------------------------------------------------------
__global__ __launch_bounds__(512) void kQ(
    const float* __restrict__ S12,   // [2048][256]
    const float* __restrict__ Aarr,  // [2048]
    const float* __restrict__ Carr,  // [2048]
    const float* __restrict__ Wb,    // [128]
    const float* __restrict__ noise, // [512][512]
    float* __restrict__ out)         // [512][512]
{
    __shared__ __align__(16) float smem[32768];   // 128 KB
    float* S1t = smem;             // [4][128][32]
    float* S2t = smem + 16384;     // [4][128][32]

    const int t = threadIdx.x;
    const int bx = blockIdx.x, by = blockIdx.y;

    // ---- stage all 4 bz tiles: 8192 float4 tasks, 16 per thread ----
#pragma unroll
    for (int q = 0; q < 16; ++q) {
        int task = q * 512 + t;
        int isS2 = task >> 12;
        int r    = task & 4095;
        int bz   = r >> 10;
        int row  = (r >> 5) & 31;
        int c4   = r & 31;
        size_t src = (size_t)(bz * NN + (isS2 ? by : bx) * 32 + row) * 256
                     + (isS2 ? 128 : 0) + c4 * 4;
        float4 v = *(const float4*)&S12[src];
        float* dst = (isS2 ? S2t : S1t) + bz * 4096;
        int rw = row ^ ((c4 & 7) << 2);          // sw = ((l>>2)&7)<<2, l = 4c4+d
        dst[(c4 * 4 + 0) * 32 + rw] = v.x;
        dst[(c4 * 4 + 1) * 32 + rw] = v.y;
        dst[(c4 * 4 + 2) * 32 + rw] = v.z;
        dst[(c4 * 4 + 3) * 32 + rw] = v.w;
    }
    __syncthreads();

    const int lh = t >> 8;           // l-half
    const int bz = (t >> 6) & 3;     // b-slice (wave-uniform)
    const int s  = t & 63;
    const int i0 = (s >> 3) << 2, j0 = (s & 7) << 2;

    const float* S1b = S1t + bz * 4096 + lh * 64 * 32;
    const float* S2b = S2t + bz * 4096 + lh * 64 * 32;
    const float* wbp = Wb + lh * 64;

    float accv[16];
#pragma unroll
    for (int k = 0; k < 16; ++k) accv[k] = 0.0f;

    for (int l4 = 0; l4 < 16; ++l4) {
        const int sw = (l4 & 7) << 2;
        const int lrow = l4 * 4 * 32;
        float4 wv = *(const float4*)&wbp[l4 * 4];   // wave-uniform broadcast
        const float wl[4] = {wv.x, wv.y, wv.z, wv.w};
#pragma unroll
        for (int d = 0; d < 4; ++d) {
            float4 a = *(const float4*)&S1b[lrow + d * 32 + (i0 ^ sw)];
            float4 b = *(const float4*)&S2b[lrow + d * 32 + (j0 ^ sw)];
            float w = wl[d];
            float ai[4] = {a.x, a.y, a.z, a.w};
            float bj[4] = {b.x, b.y, b.z, b.w};
#pragma unroll
            for (int ii = 0; ii < 4; ++ii)
#pragma unroll
                for (int jj = 0; jj < 4; ++jj) {
                    float tv = ai[ii] + bj[jj];
                    accv[ii * 4 + jj] = fmaf(fabsf(tv), w, accv[ii * 4 + jj]);
                }
        }
    }

    // ---- reduce l-halves through LDS (alias dead S1t) ----
    float* red = smem;                    // 4096 floats
    const int tid2 = t & 255;             // (bz, s)
    __syncthreads();
    if (lh) {
#pragma unroll
        for (int q = 0; q < 4; ++q) {
            float4 v = {accv[4 * q], accv[4 * q + 1], accv[4 * q + 2], accv[4 * q + 3]};
            *(float4*)&red[q * 1024 + tid2 * 4] = v;
        }
    }
    __syncthreads();

    float sig[16];
    if (!lh) {
#pragma unroll
        for (int q = 0; q < 4; ++q) {
            float4 v = *(const float4*)&red[q * 1024 + tid2 * 4];
            accv[4 * q]     += v.x;
            accv[4 * q + 1] += v.y;
            accv[4 * q + 2] += v.z;
            accv[4 * q + 3] += v.w;
        }
        float Av[4], Cv[4];
#pragma unroll
        for (int ii = 0; ii < 4; ++ii) Av[ii] = Aarr[bz * NN + bx * 32 + i0 + ii];
#pragma unroll
        for (int jj = 0; jj < 4; ++jj) Cv[jj] = Carr[bz * NN + by * 32 + j0 + jj];
#pragma unroll
        for (int ii = 0; ii < 4; ++ii)
#pragma unroll
            for (int jj = 0; jj < 4; ++jj) {
                float lg = Av[ii] + Cv[jj] + 0.4f * accv[ii * 4 + jj];
                sig[ii * 4 + jj] = 1.0f / (1.0f + expf(-lg));
            }
        // ---- bz-reduce staging: bz>=1 write sigmoids ----
        float* redB = smem + 4096;        // 3072 floats
        if (bz) {
#pragma unroll
            for (int q = 0; q < 4; ++q) {
                float4 v = {sig[4 * q], sig[4 * q + 1], sig[4 * q + 2], sig[4 * q + 3]};
                *(float4*)&redB[(bz - 1) * 1024 + q * 256 + s * 4] = v;
            }
        }
    }
    __syncthreads();

    // ---- bz=0 threads sum 4 slices, publish p[16] ----
    float* redB = smem + 4096;
    float* redP = smem + 7168;            // 1024 floats
    if (t < 64) {                          // lh=0, bz=0, s=t
#pragma unroll
        for (int bzz = 0; bzz < 3; ++bzz)
#pragma unroll
            for (int q = 0; q < 4; ++q) {
                float4 v = *(const float4*)&redB[bzz * 1024 + q * 256 + t * 4];
                sig[4 * q]     += v.x;
                sig[4 * q + 1] += v.y;
                sig[4 * q + 2] += v.z;
                sig[4 * q + 3] += v.w;
            }
#pragma unroll
        for (int q = 0; q < 4; ++q) {
            float4 v = {sig[4 * q], sig[4 * q + 1], sig[4 * q + 2], sig[4 * q + 3]};
            *(float4*)&redP[t * 16 + q * 4] = v;
        }
    }
    __syncthreads();

    // ---- phase F: 256 threads, 4 outputs each ----
    if (t < 256) {
        int i   = t >> 3;                 // 0..31
        int j0f = (t & 7) * 4;            // 0..28
        int sP  = (t >> 5) * 8 + (t & 7);
        int k0  = ((t >> 3) & 3) * 4;
        float4 pv4 = *(const float4*)&redP[sP * 16 + k0];
        float pv[4] = {pv4.x, pv4.y, pv4.z, pv4.w};

        int gi = bx * 32 + i;
        size_t base = (size_t)gi * NN + by * 32 + j0f;
        float4 nz = *(const float4*)&noise[base];
        float nv[4] = {nz.x, nz.y, nz.z, nz.w};

        float4 o;
        float* op = (float*)&o;
#pragma unroll
        for (int c = 0; c < 4; ++c) {
            float p = 0.25f * pv[c];
            int gj = by * 32 + j0f + c;
            if (gj == gi) p = 0.0f;
            float lp = logf(p + 1e-10f) - log1pf(-p + 1e-10f);
            lp = fminf(fmaxf(lp, -10.0f), 10.0f);
            float lgs = logf(nv[c]) - log1pf(-nv[c]);
            op[c] = 1.0f / (1.0f + expf(-(lp + lgs) * 5.0f));
        }
        *(float4*)&out[base] = o;
    }
}

// ---------------------------------------------------------------------------
extern "C" void kernel_launch(void* const* d_in, const int* in_sizes, int n_in,
                              void* d_out, int out_size, void* d_ws, size_t ws_size,
                              hipStream_t stream) {
    const float* x     = (const float*)d_in[0];
    const float* W1    = (const float*)d_in[1];
    const float* b1    = (const float*)d_in[2];
    const float* W2    = (const float*)d_in[3];
    const float* b2    = (const float*)d_in[4];
    const float* Wp    = (const float*)d_in[5];
    const float* bp    = (const float*)d_in[6];
    const float* Wb    = (const float*)d_in[7];
    const float* bb    = (const float*)d_in[8];
    const float* noise = (const float*)d_in[9];

    float* ws   = (float*)d_ws;
    float* S12  = ws;                   // 524288 floats
    float* Aarr = ws + 524288;          // 2048
    float* Carr = Aarr + 2048;          // 2048
    float* Wt   = Carr + 2048;          // 288*256 = 73728
    float* Wpt  = Wt + 73728;           // 128*256 = 32768

    kT<<<416, 256, 0, stream>>>(W1, W2, Wp, Wt, Wpt);
    kP<<<256, 512, 0, stream>>>(x, Wt, b1, b2, Wpt, bp, Wb, bb,
                                S12, Aarr, Carr);
    kQ<<<dim3(16, 16), 512, 0, stream>>>(S12, Aarr, Carr, Wb, noise,
                                         (float*)d_out);
}

// Round 10
// 45.311 us; speedup vs baseline: 2.3185x; 1.0025x over previous
//
#include <hip/hip_runtime.h>
#include <hip/hip_bf16.h>
#include <math.h>

// B=4, N=512, T=288, L=128
#define NN 512
#define NT 288

// ---------------------------------------------------------------------------
// Kernel T: weight re-layout (once per call, L2-resident after).
// Wt2[72][256][4]:  Wt2[k4][col][d]  = col<128 ? W1[col][k4*4+d] : W2[col-128][k4*4+d]
// Wpt2[32][256][4]: Wpt2[k4][col][d] = col<128 ? Wp[col][k4*4+d] : Wp[col-128][128+k4*4+d]
// One b128 per (k4,col) in kP. 73728 + 32768 = 106496 elements = 416x256.
// ---------------------------------------------------------------------------
__global__ __launch_bounds__(256) void kT(
    const float* __restrict__ W1, const float* __restrict__ W2,
    const float* __restrict__ Wp,
    float* __restrict__ Wt2, float* __restrict__ Wpt2)
{
    int g = blockIdx.x * 256 + threadIdx.x;
    if (g < 73728) {
        int k4 = g >> 10, col = (g >> 2) & 255, d = g & 3;
        int k = k4 * 4 + d;
        Wt2[g] = (col < 128) ? W1[col * 288 + k] : W2[(col - 128) * 288 + k];
    } else {
        int h = g - 73728;
        int k4 = h >> 10, col = (h >> 2) & 255, d = h & 3;
        int k = k4 * 4 + d;
        Wpt2[h] = (col < 128) ? Wp[col * 256 + k]
                              : Wp[(col - 128) * 256 + 128 + k];
    }
}

// ---------------------------------------------------------------------------
// Kernel P: x -> x1,x2 (leaky) -> S12=[S1|S2] + row dots A,C.
// 256 blocks x 512 threads = (col 0..255, kh 0..1), 8 bn-rows per block.
// KEY: x and x12 are read with WAVE-UNIFORM global addresses (readfirstlane
// on the K-offset) -> scalar/1-line path, ZERO LDS traffic in the GEMM loops
// (R6/R9's 3328 broadcast ds_read_b128/CU = 16.6 us was the kP wall).
// x12 roundtrips through global scratch x12g (same-block producer/consumer,
// __syncthreads drains vmcnt; values identical across graph replays).
// W via Wt2/Wpt2: one coalesced b128 per k4 per thread.
// ---------------------------------------------------------------------------
__global__ __launch_bounds__(512) void kP(
    const float* __restrict__ x,     // [2048][288]
    const float* __restrict__ Wt2,   // [72][256][4]
    const float* __restrict__ b1,    // [128]
    const float* __restrict__ b2,    // [128]
    const float* __restrict__ Wpt2,  // [32][256][4]
    const float* __restrict__ bp,    // [128]
    const float* __restrict__ Wb,    // [128]
    const float* __restrict__ bb,    // [1]
    float* __restrict__ S12,         // ws [2048][256]
    float* __restrict__ Aarr,        // ws [2048]
    float* __restrict__ Carr,        // ws [2048]
    float* __restrict__ x12g)        // ws scratch [2048][256]
{
    __shared__ __align__(16) float ph[8 * 256];    // 8 KB
    __shared__ __align__(16) float s12s[8 * 257];  // 8.2 KB

    const int t   = threadIdx.x;
    const int bn0 = blockIdx.x * 8;
    const int col = t & 255;
    const int kh  = t >> 8;       // K-half (wave-uniform: waves 0-3 vs 4-7)

    // ---- G1: col of [x1|x2] for 8 rows; K=288 split 144/144 over kh ----
    const int kb1 = __builtin_amdgcn_readfirstlane(kh * 144);  // SGPR offset
    const float* xu  = x + (size_t)bn0 * NT;                   // uniform base
    const float* wtb = Wt2 + (size_t)(kh * 36) * 1024 + col * 4;

    float acc[8];
#pragma unroll
    for (int n = 0; n < 8; ++n) acc[n] = 0.0f;

#pragma unroll 2
    for (int k4 = 0; k4 < 36; ++k4) {
        float4 w = *(const float4*)&wtb[k4 * 1024];
#pragma unroll
        for (int n = 0; n < 8; ++n) {
            float4 xv = *(const float4*)&xu[n * NT + kb1 + k4 * 4];  // uniform
            acc[n] = fmaf(w.x, xv.x, acc[n]);
            acc[n] = fmaf(w.y, xv.y, acc[n]);
            acc[n] = fmaf(w.z, xv.z, acc[n]);
            acc[n] = fmaf(w.w, xv.w, acc[n]);
        }
    }

    const float bias1 = (col < 128) ? b1[col] : b2[col - 128];
    if (kh) {
#pragma unroll
        for (int n = 0; n < 8; ++n) ph[n * 256 + col] = acc[n];
    }
    __syncthreads();
    if (!kh) {
#pragma unroll
        for (int n = 0; n < 8; ++n) {
            float v = acc[n] + ph[n * 256 + col] + bias1;
            x12g[(size_t)(bn0 + n) * 256 + col] = fmaxf(v, 0.2f * v);  // leaky
        }
    }
    __syncthreads();   // vmcnt drained: x12g visible to own block

    // ---- G2: col of [S1|S2] for 8 rows; K=128 split 64/64 over kh ----
    const int kb2 = __builtin_amdgcn_readfirstlane(((col < 128) ? 0 : 128) + kh * 64);
    const float* x2u = x12g + (size_t)bn0 * 256;               // uniform base
    const float* wpb = Wpt2 + (size_t)(kh * 16) * 1024 + col * 4;
    const float bias2 = (col < 128) ? bp[col] : 0.0f;

    float acc2[8];
#pragma unroll
    for (int n = 0; n < 8; ++n) acc2[n] = 0.0f;

#pragma unroll 2
    for (int k4 = 0; k4 < 16; ++k4) {
        float4 w = *(const float4*)&wpb[k4 * 1024];
#pragma unroll
        for (int n = 0; n < 8; ++n) {
            float4 xv = *(const float4*)&x2u[n * 256 + kb2 + k4 * 4];  // uniform
            acc2[n] = fmaf(w.x, xv.x, acc2[n]);
            acc2[n] = fmaf(w.y, xv.y, acc2[n]);
            acc2[n] = fmaf(w.z, xv.z, acc2[n]);
            acc2[n] = fmaf(w.w, xv.w, acc2[n]);
        }
    }
    if (kh) {
#pragma unroll
        for (int n = 0; n < 8; ++n) ph[n * 256 + col] = acc2[n];
    }
    __syncthreads();

    if (!kh) {
#pragma unroll
        for (int n = 0; n < 8; ++n) {
            float sv = acc2[n] + ph[n * 256 + col] + bias2;
            S12[(size_t)(bn0 + n) * 256 + col] = sv;
            s12s[n * 257 + col] = sv;
        }
    }
    __syncthreads();

    // ---- per-row dots with Wb: 16 dots x 32 lanes ----
    {
        int lane32 = t & 31;
        int n = (t >> 5) & 7;
        int isC = t >> 8;
        int base = isC ? 128 : 0;
        float sum = 0.0f;
#pragma unroll
        for (int s = 0; s < 4; ++s) {
            int j = lane32 + s * 32;
            sum = fmaf(s12s[n * 257 + base + j], Wb[j], sum);
        }
#pragma unroll
        for (int m = 16; m >= 1; m >>= 1)
            sum += __shfl_xor(sum, m, 32);
        if (lane32 == 0) {
            if (isC) Carr[bn0 + n] = 0.6f * sum;
            else     Aarr[bn0 + n] = 0.6f * sum + bb[0];
        }
    }
}

// ---------------------------------------------------------------------------
// Kernel Q: fully-fused pairwise + mean-over-b + phase F.
// grid (16,16), 1024 threads = (lq 0..3, bz 0..3, s 0..63): l split in
// QUARTERS -> 16 waves/block = 4 waves/SIMD (2x R7's latency hiding; LDS and
// VALU walls unchanged). 4x4 outputs per thread over its 32 l's.
// LDS: S1t[4][128][32] + S2t[4][128][32] = 128 KB, same verified swizzle.
// Reduce: lq (3 partial sets, 48KB alias on S1t) -> sigmoid -> bz -> F.
// ---------------------------------------------------------------------------
__global__ __launch_bounds__(1024) void kQ(
    const float* __restrict__ S12,   // [2048][256]
    const float* __restrict__ Aarr,  // [2048]
    const float* __restrict__ Carr,  // [2048]
    const float* __restrict__ Wb,    // [128]
    const float* __restrict__ noise, // [512][512]
    float* __restrict__ out)         // [512][512]
{
    __shared__ __align__(16) float smem[32768];   // 128 KB
    float* S1t = smem;             // [4][128][32]
    float* S2t = smem + 16384;     // [4][128][32]

    const int t = threadIdx.x;
    const int bx = blockIdx.x, by = blockIdx.y;

    // ---- stage all 4 bz tiles: 8192 float4 tasks, 8 per thread ----
#pragma unroll
    for (int q = 0; q < 8; ++q) {
        int task = q * 1024 + t;
        int isS2 = task >> 12;
        int r    = task & 4095;
        int bz   = r >> 10;
        int row  = (r >> 5) & 31;
        int c4   = r & 31;
        size_t src = (size_t)(bz * NN + (isS2 ? by : bx) * 32 + row) * 256
                     + (isS2 ? 128 : 0) + c4 * 4;
        float4 v = *(const float4*)&S12[src];
        float* dst = (isS2 ? S2t : S1t) + bz * 4096;
        int rw = row ^ ((c4 & 7) << 2);          // sw = ((l>>2)&7)<<2, l = 4c4+d
        dst[(c4 * 4 + 0) * 32 + rw] = v.x;
        dst[(c4 * 4 + 1) * 32 + rw] = v.y;
        dst[(c4 * 4 + 2) * 32 + rw] = v.z;
        dst[(c4 * 4 + 3) * 32 + rw] = v.w;
    }
    __syncthreads();

    const int lq = t >> 8;           // l-quarter (wave-uniform)
    const int bz = (t >> 6) & 3;     // b-slice (wave-uniform)
    const int s  = t & 63;
    const int i0 = (s >> 3) << 2, j0 = (s & 7) << 2;

    const float* S1b = S1t + bz * 4096 + lq * 32 * 32;
    const float* S2b = S2t + bz * 4096 + lq * 32 * 32;
    const float* wbp = Wb + lq * 32;

    float accv[16];
#pragma unroll
    for (int k = 0; k < 16; ++k) accv[k] = 0.0f;

    for (int l4 = 0; l4 < 8; ++l4) {
        const int sw = (l4 & 7) << 2;      // global (l>>2)&7 = (lq*8+l4)&7 = l4&7
        const int lrow = l4 * 4 * 32;
        float4 wv = *(const float4*)&wbp[l4 * 4];   // wave-uniform broadcast
        const float wl[4] = {wv.x, wv.y, wv.z, wv.w};
#pragma unroll
        for (int d = 0; d < 4; ++d) {
            float4 a = *(const float4*)&S1b[lrow + d * 32 + (i0 ^ sw)];
            float4 b = *(const float4*)&S2b[lrow + d * 32 + (j0 ^ sw)];
            float w = wl[d];
            float ai[4] = {a.x, a.y, a.z, a.w};
            float bj[4] = {b.x, b.y, b.z, b.w};
#pragma unroll
            for (int ii = 0; ii < 4; ++ii)
#pragma unroll
                for (int jj = 0; jj < 4; ++jj) {
                    float tv = ai[ii] + bj[jj];
                    accv[ii * 4 + jj] = fmaf(fabsf(tv), w, accv[ii * 4 + jj]);
                }
        }
    }

    // ---- reduce l-quarters through LDS (alias dead S1t: 48KB) ----
    float* red = smem;                    // 3 * 4096 floats
    const int tid2 = t & 255;             // (bz, s)
    __syncthreads();
    if (lq) {
#pragma unroll
        for (int q = 0; q < 4; ++q) {
            float4 v = {accv[4 * q], accv[4 * q + 1], accv[4 * q + 2], accv[4 * q + 3]};
            *(float4*)&red[(lq - 1) * 4096 + q * 1024 + tid2 * 4] = v;
        }
    }
    __syncthreads();

    float sig[16];
    float* redB = smem + 12288;           // 3072 floats
    if (!lq) {
#pragma unroll
        for (int p = 0; p < 3; ++p)
#pragma unroll
            for (int q = 0; q < 4; ++q) {
                float4 v = *(const float4*)&red[p * 4096 + q * 1024 + tid2 * 4];
                accv[4 * q]     += v.x;
                accv[4 * q + 1] += v.y;
                accv[4 * q + 2] += v.z;
                accv[4 * q + 3] += v.w;
            }
        float Av[4], Cv[4];
#pragma unroll
        for (int ii = 0; ii < 4; ++ii) Av[ii] = Aarr[bz * NN + bx * 32 + i0 + ii];
#pragma unroll
        for (int jj = 0; jj < 4; ++jj) Cv[jj] = Carr[bz * NN + by * 32 + j0 + jj];
#pragma unroll
        for (int ii = 0; ii < 4; ++ii)
#pragma unroll
            for (int jj = 0; jj < 4; ++jj) {
                float lg = Av[ii] + Cv[jj] + 0.4f * accv[ii * 4 + jj];
                sig[ii * 4 + jj] = 1.0f / (1.0f + expf(-lg));
            }
        // bz-reduce staging: bz>=1 write sigmoids
        if (bz) {
#pragma unroll
            for (int q = 0; q < 4; ++q) {
                float4 v = {sig[4 * q], sig[4 * q + 1], sig[4 * q + 2], sig[4 * q + 3]};
                *(float4*)&redB[(bz - 1) * 1024 + q * 256 + s * 4] = v;
            }
        }
    }
    __syncthreads();

    // ---- lq=0,bz=0 threads sum 4 slices, publish p[16] ----
    float* redP = smem + 15360;           // 1024 floats
    if (t < 64) {                          // lq=0, bz=0, s=t
#pragma unroll
        for (int bzz = 0; bzz < 3; ++bzz)
#pragma unroll
            for (int q = 0; q < 4; ++q) {
                float4 v = *(const float4*)&redB[bzz * 1024 + q * 256 + t * 4];
                sig[4 * q]     += v.x;
                sig[4 * q + 1] += v.y;
                sig[4 * q + 2] += v.z;
                sig[4 * q + 3] += v.w;
            }
#pragma unroll
        for (int q = 0; q < 4; ++q) {
            float4 v = {sig[4 * q], sig[4 * q + 1], sig[4 * q + 2], sig[4 * q + 3]};
            *(float4*)&redP[t * 16 + q * 4] = v;
        }
    }
    __syncthreads();

    // ---- phase F: 256 threads, 4 outputs each ----
    if (t < 256) {
        int i   = t >> 3;                 // 0..31
        int j0f = (t & 7) * 4;            // 0..28
        int sP  = (t >> 5) * 8 + (t & 7);
        int k0  = ((t >> 3) & 3) * 4;
        float4 pv4 = *(const float4*)&redP[sP * 16 + k0];
        float pv[4] = {pv4.x, pv4.y, pv4.z, pv4.w};

        int gi = bx * 32 + i;
        size_t base = (size_t)gi * NN + by * 32 + j0f;
        float4 nz = *(const float4*)&noise[base];
        float nv[4] = {nz.x, nz.y, nz.z, nz.w};

        float4 o;
        float* op = (float*)&o;
#pragma unroll
        for (int c = 0; c < 4; ++c) {
            float p = 0.25f * pv[c];
            int gj = by * 32 + j0f + c;
            if (gj == gi) p = 0.0f;
            float lp = logf(p + 1e-10f) - log1pf(-p + 1e-10f);
            lp = fminf(fmaxf(lp, -10.0f), 10.0f);
            float lgs = logf(nv[c]) - log1pf(-nv[c]);
            op[c] = 1.0f / (1.0f + expf(-(lp + lgs) * 5.0f));
        }
        *(float4*)&out[base] = o;
    }
}

// ---------------------------------------------------------------------------
extern "C" void kernel_launch(void* const* d_in, const int* in_sizes, int n_in,
                              void* d_out, int out_size, void* d_ws, size_t ws_size,
                              hipStream_t stream) {
    const float* x     = (const float*)d_in[0];
    const float* W1    = (const float*)d_in[1];
    const float* b1    = (const float*)d_in[2];
    const float* W2    = (const float*)d_in[3];
    const float* b2    = (const float*)d_in[4];
    const float* Wp    = (const float*)d_in[5];
    const float* bp    = (const float*)d_in[6];
    const float* Wb    = (const float*)d_in[7];
    const float* bb    = (const float*)d_in[8];
    const float* noise = (const float*)d_in[9];

    float* ws   = (float*)d_ws;
    float* S12  = ws;                   // 524288 floats
    float* Aarr = ws + 524288;          // 2048
    float* Carr = Aarr + 2048;          // 2048
    float* Wt2  = Carr + 2048;          // 73728
    float* Wpt2 = Wt2 + 73728;          // 32768
    float* x12g = Wpt2 + 32768;         // 524288

    kT<<<416, 256, 0, stream>>>(W1, W2, Wp, Wt2, Wpt2);
    kP<<<256, 512, 0, stream>>>(x, Wt2, b1, b2, Wpt2, bp, Wb, bb,
                                S12, Aarr, Carr, x12g);
    kQ<<<dim3(16, 16), 1024, 0, stream>>>(S12, Aarr, Carr, Wb, noise,
                                          (float*)d_out);
}